// Round 13
// baseline (244.054 us; speedup 1.0000x reference)
//
#include <hip/hip_runtime.h>
#include <hip/hip_bf16.h>

typedef short short8 __attribute__((ext_vector_type(8)));
typedef float f32x4 __attribute__((ext_vector_type(4)));
typedef float f32x16 __attribute__((ext_vector_type(16)));
typedef unsigned short u16;
typedef unsigned int u32;

#define HD 16
#define DMODEL 1024
#define DKH 64
#define SEQ 2048
#define QSCALE 0.18033688f  // 1/sqrt(64) * log2(e)

typedef const __attribute__((address_space(1))) void gvoid;
typedef __attribute__((address_space(3))) void lvoid;

__device__ inline u16 f2bf(float f) {
  unsigned int x = __builtin_bit_cast(unsigned int, f);
  unsigned int r = (x + 0x7fffu + ((x >> 16) & 1u)) >> 16;
  return (u16)r;
}

__device__ inline float fexp2(float x) {
#if __has_builtin(__builtin_amdgcn_exp2f)
  return __builtin_amdgcn_exp2f(x);
#else
  return __expf(x * 0.69314718f);
#endif
}

__device__ inline u32 cvtpk(float lo, float hi_) {
  u32 r;
  asm("v_cvt_pk_bf16_f32 %0, %1, %2" : "=v"(r) : "v"(lo), "v"(hi_));
  return r;
}

// swap a.hi(lanes32-63) <-> b.lo(lanes0-31)
__device__ inline void pswap(u32& a, u32& b) {
  asm volatile("v_permlane32_swap_b32 %0, %1" : "+v"(a), "+v"(b));
}

__device__ inline f32x4 mfma16(short8 a, short8 b, f32x4 c) {
  return __builtin_amdgcn_mfma_f32_16x16x32_bf16(a, b, c, 0, 0, 0);
}
__device__ inline f32x16 mfma32(short8 a, short8 b, f32x16 c) {
  return __builtin_amdgcn_mfma_f32_32x32x16_bf16(a, b, c, 0, 0, 0);
}

// ---------------- prep: z<3 convert q/k/v fp32->bf16 ; z=3 weight transpose ----------------
__global__ __launch_bounds__(256) void prep_kernel(const float* __restrict__ q,
                                                   const float* __restrict__ k,
                                                   const float* __restrict__ v,
                                                   const float* __restrict__ W0,
                                                   const float* __restrict__ W1,
                                                   const float* __restrict__ W2,
                                                   const float* __restrict__ W3,
                                                   u16* __restrict__ Qf,
                                                   u16* __restrict__ Kf,
                                                   u16* __restrict__ Vf,
                                                   u16* __restrict__ WT) {
  const int z = blockIdx.z;
  if (z < 3) {
    const float* src = z == 0 ? q : z == 1 ? k : v;
    u16* dst = z == 0 ? Qf : z == 1 ? Kf : Vf;
    const int nthr = gridDim.x * 256;
    for (size_t i = blockIdx.x * 256 + threadIdx.x; i < (size_t)(SEQ * 4) * DMODEL / 8; i += nthr) {
      const float4 a0 = *(const float4*)(src + i * 8);
      const float4 a1 = *(const float4*)(src + i * 8 + 4);
      u32 tmp[4] = {cvtpk(a0.x, a0.y), cvtpk(a0.z, a0.w),
                    cvtpk(a1.x, a1.y), cvtpk(a1.z, a1.w)};
      *(uint4*)(dst + i * 8) = *(uint4*)tmp;
    }
  } else {
    __shared__ float tile[64][65];
    const int b = blockIdx.x;
    const int w = b >> 8;
    const int n0 = (b & 15) * 64, k0 = ((b >> 4) & 15) * 64;
    const float* W = w == 0 ? W0 : w == 1 ? W1 : w == 2 ? W2 : W3;
    u16* out = WT + (size_t)w * DMODEL * DMODEL;
    int tx = threadIdx.x & 63, ty = threadIdx.x >> 6;
    for (int i = 0; i < 16; i++) {
      int r = ty + i * 4;
      tile[r][tx] = W[(size_t)(k0 + r) * DMODEL + n0 + tx];
    }
    __syncthreads();
    for (int i = 0; i < 16; i++) {
      int r = ty + i * 4;
      out[(size_t)(n0 + r) * DMODEL + k0 + tx] = f2bf(tile[tx][r]);
    }
  }
}

// ---------------- fused QKV GEMM v4 (unchanged): all-bf16, glds, 2-stage pipeline ----
__global__ __launch_bounds__(256, 2) void gemm_qkv(const u16* __restrict__ Qf,
                                                   const u16* __restrict__ Kf,
                                                   const u16* __restrict__ Vf,
                                                   const u16* __restrict__ WT,
                                                   const float* __restrict__ bq,
                                                   const float* __restrict__ bk,
                                                   const float* __restrict__ bv,
                                                   u16* __restrict__ Qb,
                                                   u16* __restrict__ Kb,
                                                   u16* __restrict__ Vtb) {
  __shared__ u16 As[2][128 * 64];
  __shared__ u16 Bs[2][128 * 64];
  const int b = blockIdx.x;
  const int xcd = b & 7, slot = b >> 3;
  const int nidx = slot & 7, pl = slot >> 3;
  const int pg = xcd * 24 + pl;
  const int z = pg >> 6, by = pg & 63;

  const u16* A = z == 0 ? Qf : z == 1 ? Kf : Vf;
  const u16* Bt = WT + (size_t)z * DMODEL * DMODEL;
  const float* bias = z == 0 ? bq : z == 1 ? bk : bv;
  u16* Cv = z == 0 ? Qb : z == 1 ? Kb : Vtb;
  const float scale = z == 0 ? QSCALE : 1.0f;
  const bool vtrans = (z == 2);

  const int m0 = by * 128, n0 = nidx * 128;
  const int tid = threadIdx.x;
  const int lane = tid & 63, wid = tid >> 6;
  const int g = lane >> 4, c = lane & 15;
  const int wr = (wid >> 1) * 64, wc = (wid & 1) * 64;

  const int trow = tid >> 3;
  const int tcolb = (tid & 7) << 4;
  const int swr = (c & 7) << 4;
  f32x4 acc[4][4] = {};

#define STAGE_AB(buf, kk0)                                                            \
  _Pragma("unroll") for (int p = 0; p < 4; ++p) {                                     \
    const int row = p * 32 + trow;                                                    \
    const int scol = tcolb ^ ((row & 7) << 4);                                        \
    __builtin_amdgcn_global_load_lds(                                                 \
        (gvoid*)((const char*)A + ((size_t)(m0 + row) * DMODEL + (kk0)) * 2 + scol),  \
        (lvoid*)((char*)&As[buf][0] + row * 128 + tcolb), 16, 0, 0);                  \
    __builtin_amdgcn_global_load_lds(                                                 \
        (gvoid*)((const char*)Bt + ((size_t)(n0 + row) * DMODEL + (kk0)) * 2 + scol), \
        (lvoid*)((char*)&Bs[buf][0] + row * 128 + tcolb), 16, 0, 0);                  \
  }

  STAGE_AB(0, 0);
  STAGE_AB(1, 64);
  __syncthreads();

  for (int t = 0; t < 16; ++t) {
    const int cur = t & 1;
    short8 af[4][2], bfr[4][2];
#pragma unroll
    for (int kk = 0; kk < 2; ++kk) {
#pragma unroll
      for (int mi = 0; mi < 4; ++mi)
        af[mi][kk] = *(const short8*)((const char*)&As[cur][0] + (wr + mi * 16 + c) * 128 + ((kk * 64 + g * 16) ^ swr));
#pragma unroll
      for (int ni = 0; ni < 4; ++ni)
        bfr[ni][kk] = *(const short8*)((const char*)&Bs[cur][0] + (wc + ni * 16 + c) * 128 + ((kk * 64 + g * 16) ^ swr));
    }
    __builtin_amdgcn_s_setprio(1);
#pragma unroll
    for (int kk = 0; kk < 2; ++kk)
#pragma unroll
      for (int mi = 0; mi < 4; ++mi)
#pragma unroll
        for (int ni = 0; ni < 4; ++ni)
          acc[mi][ni] = mfma16(af[mi][kk], bfr[ni][kk], acc[mi][ni]);
    __builtin_amdgcn_s_setprio(0);
    __syncthreads();
    if (t < 14) STAGE_AB(cur, (t + 2) * 64);
  }
#undef STAGE_AB

  for (int ni = 0; ni < 4; ++ni) {
    const int colg = n0 + wc + ni * 16 + c;
    const float bv_ = bias[colg];
    for (int mi = 0; mi < 4; ++mi) {
      const int rowb = m0 + wr + mi * 16 + g * 4;
      const int bb = rowb >> 11, s = rowb & 2047;
      const int h = colg >> 6, dk = colg & 63;
      if (!vtrans) {
        const size_t base = ((size_t)(bb * HD + h)) * SEQ;
        for (int j = 0; j < 4; ++j)
          Cv[(base + s + j) * DKH + dk] = f2bf((acc[mi][ni][j] + bv_) * scale);
      } else {
        const size_t base = ((size_t)(bb * HD + h) * DKH + dk) * SEQ + s;
        ushort4 u;
        u.x = f2bf(acc[mi][ni][0] + bv_);
        u.y = f2bf(acc[mi][ni][1] + bv_);
        u.z = f2bf(acc[mi][ni][2] + bv_);
        u.w = f2bf(acc[mi][ni][3] + bv_);
        *(ushort4*)(&Cv[base]) = u;
      }
    }
  }
}

// ---------------- output GEMM v3 (unchanged) ----------------
__global__ __launch_bounds__(256, 2) void gemm_out(const u16* __restrict__ A,
                                                   const u16* __restrict__ Bt,
                                                   const float* __restrict__ bias,
                                                   float* __restrict__ C) {
  __shared__ u16 As[2][128 * 64];
  __shared__ u16 Bs[2][128 * 64];
  const int b = blockIdx.x;
  const int xcd = b & 7, slot = b >> 3;
  const int nidx = slot & 7, pl = slot >> 3;
  const int by = xcd * 8 + pl;

  const int m0 = by * 128, n0 = nidx * 128;
  const int tid = threadIdx.x;
  const int lane = tid & 63, wid = tid >> 6;
  const int g = lane >> 4, c = lane & 15;
  const int wr = (wid >> 1) * 64, wc = (wid & 1) * 64;

  const int trow = tid >> 3;
  const int tcolb = (tid & 7) << 4;
  const int swr = (c & 7) << 4;
  f32x4 acc[4][4] = {};

#define STAGE_AB(buf, kk0)                                                            \
  _Pragma("unroll") for (int p = 0; p < 4; ++p) {                                     \
    const int row = p * 32 + trow;                                                    \
    const int scol = tcolb ^ ((row & 7) << 4);                                        \
    __builtin_amdgcn_global_load_lds(                                                 \
        (gvoid*)((const char*)A + ((size_t)(m0 + row) * DMODEL + (kk0)) * 2 + scol),  \
        (lvoid*)((char*)&As[buf][0] + row * 128 + tcolb), 16, 0, 0);                  \
    __builtin_amdgcn_global_load_lds(                                                 \
        (gvoid*)((const char*)Bt + ((size_t)(n0 + row) * DMODEL + (kk0)) * 2 + scol), \
        (lvoid*)((char*)&Bs[buf][0] + row * 128 + tcolb), 16, 0, 0);                  \
  }

  STAGE_AB(0, 0);
  STAGE_AB(1, 64);
  __syncthreads();

  for (int t = 0; t < 16; ++t) {
    const int cur = t & 1;
    short8 af[4][2], bfr[4][2];
#pragma unroll
    for (int kk = 0; kk < 2; ++kk) {
#pragma unroll
      for (int mi = 0; mi < 4; ++mi)
        af[mi][kk] = *(const short8*)((const char*)&As[cur][0] + (wr + mi * 16 + c) * 128 + ((kk * 64 + g * 16) ^ swr));
#pragma unroll
      for (int ni = 0; ni < 4; ++ni)
        bfr[ni][kk] = *(const short8*)((const char*)&Bs[cur][0] + (wc + ni * 16 + c) * 128 + ((kk * 64 + g * 16) ^ swr));
    }
    __builtin_amdgcn_s_setprio(1);
#pragma unroll
    for (int kk = 0; kk < 2; ++kk)
#pragma unroll
      for (int mi = 0; mi < 4; ++mi)
#pragma unroll
        for (int ni = 0; ni < 4; ++ni)
          acc[mi][ni] = mfma16(af[mi][kk], bfr[ni][kk], acc[mi][ni]);
    __builtin_amdgcn_s_setprio(0);
    __syncthreads();
    if (t < 14) STAGE_AB(cur, (t + 2) * 64);
  }
#undef STAGE_AB

  for (int ni = 0; ni < 4; ++ni) {
    const int colg = n0 + wc + ni * 16 + c;
    const float bv = bias[colg];
    for (int mi = 0; mi < 4; ++mi) {
      const int rowb = m0 + wr + mi * 16 + g * 4;
      for (int j = 0; j < 4; ++j)
        C[(size_t)(rowb + j) * DMODEL + colg] = acc[mi][ni][j] + bv;
    }
  }
}

// ---------------- flash attention v9: counted-vmcnt + hoisted V-frags + VALU row-sum ----
// R8's proven softmax (rs-sum, no ones-column). All 16 K+V fragment ds_reads issued
// at body top so V's LDS latency drains under QK+softmax instead of inside PV.
__global__ __launch_bounds__(256, 4) void attn_kernel(const u16* __restrict__ Q,
                                                      const u16* __restrict__ K,
                                                      const u16* __restrict__ Vt,
                                                      u16* __restrict__ X) {
  __shared__ char Kls[3][8192];
  __shared__ char Vls[2][8192];
  const int tid = threadIdx.x;
  const int lane = tid & 63, wid = tid >> 6;
  const int c5 = lane & 31, hi = lane >> 5;

  const int blk = blockIdx.x;
  const int work = (blk & 7) * 128 + (blk >> 3);
  const int qt = work & 15, bh = work >> 4;

  const int q0 = qt * 128 + wid * 32;
  const u16* qb = Q + (size_t)bh * SEQ * DKH;
  const char* kbB = (const char*)(K + (size_t)bh * SEQ * DKH);
  const char* vbB = (const char*)(Vt + (size_t)bh * DKH * SEQ);

  short8 qf[4];
#pragma unroll
  for (int ks = 0; ks < 4; ++ks)
    qf[ks] = *(const short8*)(qb + (size_t)(q0 + c5) * DKH + ks * 16 + hi * 8);

  const int srow = tid >> 3;
  const int scolb = (tid & 7) << 4;
  const int scol = scolb ^ ((srow & 7) << 4);

  const int fswz = (c5 & 7) << 4;
  int cofs[4];
#pragma unroll
  for (int ks = 0; ks < 4; ++ks) cofs[ks] = ((ks * 32 + hi * 16) ^ fswz);

  f32x16 oacc[2] = {};
  float lrun = 0.f;

#define STAGE_K(t, dst)                                                         \
  _Pragma("unroll") for (int r32 = 0; r32 < 64; r32 += 32)                      \
      __builtin_amdgcn_global_load_lds(                                         \
          (gvoid*)(kbB + ((size_t)(t) * 64 + r32 + srow) * 128 + scol),         \
          (lvoid*)((dst) + (r32 + srow) * 128 + scolb), 16, 0, 0);
#define STAGE_V(t, dst)                                                         \
  _Pragma("unroll") for (int r32 = 0; r32 < 64; r32 += 32)                      \
      __builtin_amdgcn_global_load_lds(                                         \
          (gvoid*)(vbB + (size_t)(r32 + srow) * (SEQ * 2) + (size_t)(t) * 128 + scol), \
          (lvoid*)((dst) + (r32 + srow) * 128 + scolb), 16, 0, 0);

  // prologue: V(0), K(0), K(1); counted wait leaves K(1) in flight
  STAGE_V(0, Vls[0]);
  STAGE_K(0, Kls[0]);
  STAGE_K(1, Kls[1]);
  asm volatile("s_waitcnt vmcnt(2)" ::: "memory");
  __builtin_amdgcn_s_barrier();
  __builtin_amdgcn_sched_barrier(0);

  char* pk0 = Kls[0];
  char* pk1 = Kls[1];
  char* pk2 = Kls[2];

  for (int t = 0; t < 32; ++t) {
    // issue next-tile loads: V first, K second (FIFO order for counted vmcnt)
    if (t < 31) STAGE_V(t + 1, Vls[(t + 1) & 1]);
    if (t < 30) STAGE_K(t + 2, pk2);

    // hoist ALL fragment reads: K for QK now, V for PV later (latency drains
    // under the QK MFMAs + softmax VALU phase)
    const char* bV = Vls[t & 1];
    short8 kf[2][4], vf[2][4];
#pragma unroll
    for (int kt = 0; kt < 2; ++kt)
#pragma unroll
      for (int ks = 0; ks < 4; ++ks)
        kf[kt][ks] = *(const short8*)(pk0 + (kt * 32 + c5) * 128 + cofs[ks]);
#pragma unroll
    for (int dkt = 0; dkt < 2; ++dkt)
#pragma unroll
      for (int ks = 0; ks < 4; ++ks)
        vf[dkt][ks] = *(const short8*)(bV + (dkt * 32 + c5) * 128 + cofs[ks]);

    // S^T = K * Q^T
    f32x16 sacc[2];
    __builtin_amdgcn_s_setprio(1);
#pragma unroll
    for (int kt = 0; kt < 2; ++kt) {
      sacc[kt] = (f32x16){};
#pragma unroll
      for (int ks = 0; ks < 4; ++ks)
        sacc[kt] = mfma32(kf[kt][ks], qf[ks], sacc[kt]);
    }
    __builtin_amdgcn_s_setprio(0);

    // softmax (no max; R8 form): p = exp2(s), row-sum on VALU, pack to bf16
    float rs = 0.f;
    u32 W[2][8];
#pragma unroll
    for (int kt = 0; kt < 2; ++kt)
#pragma unroll
      for (int j = 0; j < 8; ++j) {
        float p0 = fexp2(sacc[kt][2 * j]);
        float p1 = fexp2(sacc[kt][2 * j + 1]);
        rs += p0 + p1;
        W[kt][j] = cvtpk(p0, p1);
      }
    rs += __shfl_xor(rs, 32, 64);
    lrun += rs;

    short8 pa[4];
#pragma unroll
    for (int ks = 0; ks < 4; ++ks) {
      const int kt = ks >> 1, l4 = (ks & 1) * 4;
      u32 a0 = W[kt][l4 + 0], b0 = W[kt][l4 + 2];
      u32 a1 = W[kt][l4 + 1], b1 = W[kt][l4 + 3];
      pswap(a0, b0);
      pswap(a1, b1);
      u32 tmp[4] = {a0, a1, b0, b1};
      pa[ks] = *(const short8*)tmp;
    }

    // PV from hoisted vf
    __builtin_amdgcn_s_setprio(1);
#pragma unroll
    for (int ks = 0; ks < 4; ++ks)
#pragma unroll
      for (int dkt = 0; dkt < 2; ++dkt)
        oacc[dkt] = mfma32(pa[ks], vf[dkt][ks], oacc[dkt]);
    __builtin_amdgcn_s_setprio(0);

    // counted wait: V(t+1)/K(t+1) landed; K(t+2) stays in flight
    if (t < 30) {
      asm volatile("s_waitcnt vmcnt(2)" ::: "memory");
    } else {
      asm volatile("s_waitcnt vmcnt(0)" ::: "memory");
    }
    __builtin_amdgcn_s_barrier();
    __builtin_amdgcn_sched_barrier(0);

    char* tmpk = pk0;
    pk0 = pk1;
    pk1 = pk2;
    pk2 = tmpk;
  }

#undef STAGE_K
#undef STAGE_V

  // epilogue
  const int b = bh >> 4, h = bh & 15;
  const float inv = 1.0f / lrun;
#pragma unroll
  for (int r = 0; r < 16; ++r) {
    const int qrow = (r & 3) + 8 * (r >> 2) + 4 * hi;
    const float linv = __shfl(inv, qrow, 64);
    const size_t rowbase = ((size_t)(b * SEQ) + q0 + qrow) * DMODEL + h * DKH;
#pragma unroll
    for (int dkt = 0; dkt < 2; ++dkt)
      X[rowbase + dkt * 32 + c5] = f2bf(oacc[dkt][r] * linv);
  }
}

extern "C" void kernel_launch(void* const* d_in, const int* in_sizes, int n_in,
                              void* d_out, int out_size, void* d_ws, size_t ws_size,
                              hipStream_t stream) {
  (void)in_sizes; (void)n_in; (void)out_size; (void)ws_size;
  const float* query = (const float*)d_in[0];
  const float* key   = (const float*)d_in[1];
  const float* value = (const float*)d_in[2];
  const float* Wq = (const float*)d_in[3];
  const float* bq = (const float*)d_in[4];
  const float* Wk = (const float*)d_in[5];
  const float* bk = (const float*)d_in[6];
  const float* Wv = (const float*)d_in[7];
  const float* bv = (const float*)d_in[8];
  const float* Wo = (const float*)d_in[9];
  const float* bo = (const float*)d_in[10];
  float* out = (float*)d_out;

  char* ws = (char*)d_ws;
  const size_t MB = 1024 * 1024;
  u16* WT  = (u16*)ws;                  // 0-8 MB: WqT, WkT, WvT, WoT
  u16* Qf  = (u16*)(ws + 8 * MB);       // 8-24  bf16 query
  u16* Kf  = (u16*)(ws + 24 * MB);      // 24-40 bf16 key
  u16* Vf  = (u16*)(ws + 40 * MB);      // 40-56 bf16 value
  u16* Qb  = (u16*)(ws + 56 * MB);      // 56-72
  u16* Kb  = (u16*)(ws + 72 * MB);      // 72-88
  u16* Vtb = (u16*)(ws + 88 * MB);      // 88-104
  u16* Xb  = (u16*)(ws + 8 * MB);       // aliases Qf (dead after gemm_qkv)

  prep_kernel<<<dim3(1024, 1, 4), 256, 0, stream>>>(query, key, value, Wq, Wk, Wv, Wo,
                                                    Qf, Kf, Vf, WT);
  gemm_qkv<<<dim3(1536), 256, 0, stream>>>(Qf, Kf, Vf, WT, bq, bk, bv, Qb, Kb, Vtb);
  attn_kernel<<<dim3(1024), 256, 0, stream>>>(Qb, Kb, Vtb, Xb);
  gemm_out<<<dim3(512), 256, 0, stream>>>(Xb, WT + 3 * 1048576, bo, out);
}

// Round 14
// 187.482 us; speedup vs baseline: 1.3017x; 1.3017x over previous
//
#include <hip/hip_runtime.h>
#include <hip/hip_bf16.h>

typedef short short8 __attribute__((ext_vector_type(8)));
typedef float f32x4 __attribute__((ext_vector_type(4)));
typedef float f32x16 __attribute__((ext_vector_type(16)));
typedef unsigned short u16;
typedef unsigned int u32;

#define HD 16
#define DMODEL 1024
#define DKH 64
#define SEQ 2048
#define QSCALE 0.18033688f  // 1/sqrt(64) * log2(e)

typedef const __attribute__((address_space(1))) void gvoid;
typedef __attribute__((address_space(3))) void lvoid;

__device__ inline u16 f2bf(float f) {
  unsigned int x = __builtin_bit_cast(unsigned int, f);
  unsigned int r = (x + 0x7fffu + ((x >> 16) & 1u)) >> 16;
  return (u16)r;
}

__device__ inline float fexp2(float x) {
#if __has_builtin(__builtin_amdgcn_exp2f)
  return __builtin_amdgcn_exp2f(x);
#else
  return __expf(x * 0.69314718f);
#endif
}

__device__ inline u32 cvtpk(float lo, float hi_) {
  u32 r;
  asm("v_cvt_pk_bf16_f32 %0, %1, %2" : "=v"(r) : "v"(lo), "v"(hi_));
  return r;
}

// swap a.hi(lanes32-63) <-> b.lo(lanes0-31)
__device__ inline void pswap(u32& a, u32& b) {
  asm volatile("v_permlane32_swap_b32 %0, %1" : "+v"(a), "+v"(b));
}

__device__ inline f32x4 mfma16(short8 a, short8 b, f32x4 c) {
  return __builtin_amdgcn_mfma_f32_16x16x32_bf16(a, b, c, 0, 0, 0);
}
__device__ inline f32x16 mfma32(short8 a, short8 b, f32x16 c) {
  return __builtin_amdgcn_mfma_f32_32x32x16_bf16(a, b, c, 0, 0, 0);
}

// ---------------- prep: z<3 convert q/k/v fp32->bf16 ; z=3 weight transpose ----------------
__global__ __launch_bounds__(256) void prep_kernel(const float* __restrict__ q,
                                                   const float* __restrict__ k,
                                                   const float* __restrict__ v,
                                                   const float* __restrict__ W0,
                                                   const float* __restrict__ W1,
                                                   const float* __restrict__ W2,
                                                   const float* __restrict__ W3,
                                                   u16* __restrict__ Qf,
                                                   u16* __restrict__ Kf,
                                                   u16* __restrict__ Vf,
                                                   u16* __restrict__ WT) {
  const int z = blockIdx.z;
  if (z < 3) {
    const float* src = z == 0 ? q : z == 1 ? k : v;
    u16* dst = z == 0 ? Qf : z == 1 ? Kf : Vf;
    const int nthr = gridDim.x * 256;
    for (size_t i = blockIdx.x * 256 + threadIdx.x; i < (size_t)(SEQ * 4) * DMODEL / 8; i += nthr) {
      const float4 a0 = *(const float4*)(src + i * 8);
      const float4 a1 = *(const float4*)(src + i * 8 + 4);
      u32 tmp[4] = {cvtpk(a0.x, a0.y), cvtpk(a0.z, a0.w),
                    cvtpk(a1.x, a1.y), cvtpk(a1.z, a1.w)};
      *(uint4*)(dst + i * 8) = *(uint4*)tmp;
    }
  } else {
    __shared__ float tile[64][65];
    const int b = blockIdx.x;
    const int w = b >> 8;
    const int n0 = (b & 15) * 64, k0 = ((b >> 4) & 15) * 64;
    const float* W = w == 0 ? W0 : w == 1 ? W1 : w == 2 ? W2 : W3;
    u16* out = WT + (size_t)w * DMODEL * DMODEL;
    int tx = threadIdx.x & 63, ty = threadIdx.x >> 6;
    for (int i = 0; i < 16; i++) {
      int r = ty + i * 4;
      tile[r][tx] = W[(size_t)(k0 + r) * DMODEL + n0 + tx];
    }
    __syncthreads();
    for (int i = 0; i < 16; i++) {
      int r = ty + i * 4;
      out[(size_t)(n0 + r) * DMODEL + k0 + tx] = f2bf(tile[tx][r]);
    }
  }
}

// ---------------- fused QKV GEMM v4 (unchanged): all-bf16, glds, 2-stage pipeline ----
__global__ __launch_bounds__(256, 2) void gemm_qkv(const u16* __restrict__ Qf,
                                                   const u16* __restrict__ Kf,
                                                   const u16* __restrict__ Vf,
                                                   const u16* __restrict__ WT,
                                                   const float* __restrict__ bq,
                                                   const float* __restrict__ bk,
                                                   const float* __restrict__ bv,
                                                   u16* __restrict__ Qb,
                                                   u16* __restrict__ Kb,
                                                   u16* __restrict__ Vtb) {
  __shared__ u16 As[2][128 * 64];
  __shared__ u16 Bs[2][128 * 64];
  const int b = blockIdx.x;
  const int xcd = b & 7, slot = b >> 3;
  const int nidx = slot & 7, pl = slot >> 3;
  const int pg = xcd * 24 + pl;
  const int z = pg >> 6, by = pg & 63;

  const u16* A = z == 0 ? Qf : z == 1 ? Kf : Vf;
  const u16* Bt = WT + (size_t)z * DMODEL * DMODEL;
  const float* bias = z == 0 ? bq : z == 1 ? bk : bv;
  u16* Cv = z == 0 ? Qb : z == 1 ? Kb : Vtb;
  const float scale = z == 0 ? QSCALE : 1.0f;
  const bool vtrans = (z == 2);

  const int m0 = by * 128, n0 = nidx * 128;
  const int tid = threadIdx.x;
  const int lane = tid & 63, wid = tid >> 6;
  const int g = lane >> 4, c = lane & 15;
  const int wr = (wid >> 1) * 64, wc = (wid & 1) * 64;

  const int trow = tid >> 3;
  const int tcolb = (tid & 7) << 4;
  const int swr = (c & 7) << 4;
  f32x4 acc[4][4] = {};

#define STAGE_AB(buf, kk0)                                                            \
  _Pragma("unroll") for (int p = 0; p < 4; ++p) {                                     \
    const int row = p * 32 + trow;                                                    \
    const int scol = tcolb ^ ((row & 7) << 4);                                        \
    __builtin_amdgcn_global_load_lds(                                                 \
        (gvoid*)((const char*)A + ((size_t)(m0 + row) * DMODEL + (kk0)) * 2 + scol),  \
        (lvoid*)((char*)&As[buf][0] + row * 128 + tcolb), 16, 0, 0);                  \
    __builtin_amdgcn_global_load_lds(                                                 \
        (gvoid*)((const char*)Bt + ((size_t)(n0 + row) * DMODEL + (kk0)) * 2 + scol), \
        (lvoid*)((char*)&Bs[buf][0] + row * 128 + tcolb), 16, 0, 0);                  \
  }

  STAGE_AB(0, 0);
  STAGE_AB(1, 64);
  __syncthreads();

  for (int t = 0; t < 16; ++t) {
    const int cur = t & 1;
    short8 af[4][2], bfr[4][2];
#pragma unroll
    for (int kk = 0; kk < 2; ++kk) {
#pragma unroll
      for (int mi = 0; mi < 4; ++mi)
        af[mi][kk] = *(const short8*)((const char*)&As[cur][0] + (wr + mi * 16 + c) * 128 + ((kk * 64 + g * 16) ^ swr));
#pragma unroll
      for (int ni = 0; ni < 4; ++ni)
        bfr[ni][kk] = *(const short8*)((const char*)&Bs[cur][0] + (wc + ni * 16 + c) * 128 + ((kk * 64 + g * 16) ^ swr));
    }
    __builtin_amdgcn_s_setprio(1);
#pragma unroll
    for (int kk = 0; kk < 2; ++kk)
#pragma unroll
      for (int mi = 0; mi < 4; ++mi)
#pragma unroll
        for (int ni = 0; ni < 4; ++ni)
          acc[mi][ni] = mfma16(af[mi][kk], bfr[ni][kk], acc[mi][ni]);
    __builtin_amdgcn_s_setprio(0);
    __syncthreads();
    if (t < 14) STAGE_AB(cur, (t + 2) * 64);
  }
#undef STAGE_AB

  for (int ni = 0; ni < 4; ++ni) {
    const int colg = n0 + wc + ni * 16 + c;
    const float bv_ = bias[colg];
    for (int mi = 0; mi < 4; ++mi) {
      const int rowb = m0 + wr + mi * 16 + g * 4;
      const int bb = rowb >> 11, s = rowb & 2047;
      const int h = colg >> 6, dk = colg & 63;
      if (!vtrans) {
        const size_t base = ((size_t)(bb * HD + h)) * SEQ;
        for (int j = 0; j < 4; ++j)
          Cv[(base + s + j) * DKH + dk] = f2bf((acc[mi][ni][j] + bv_) * scale);
      } else {
        const size_t base = ((size_t)(bb * HD + h) * DKH + dk) * SEQ + s;
        ushort4 u;
        u.x = f2bf(acc[mi][ni][0] + bv_);
        u.y = f2bf(acc[mi][ni][1] + bv_);
        u.z = f2bf(acc[mi][ni][2] + bv_);
        u.w = f2bf(acc[mi][ni][3] + bv_);
        *(ushort4*)(&Cv[base]) = u;
      }
    }
  }
}

// ---------------- output GEMM v3 (unchanged) ----------------
__global__ __launch_bounds__(256, 2) void gemm_out(const u16* __restrict__ A,
                                                   const u16* __restrict__ Bt,
                                                   const float* __restrict__ bias,
                                                   float* __restrict__ C) {
  __shared__ u16 As[2][128 * 64];
  __shared__ u16 Bs[2][128 * 64];
  const int b = blockIdx.x;
  const int xcd = b & 7, slot = b >> 3;
  const int nidx = slot & 7, pl = slot >> 3;
  const int by = xcd * 8 + pl;

  const int m0 = by * 128, n0 = nidx * 128;
  const int tid = threadIdx.x;
  const int lane = tid & 63, wid = tid >> 6;
  const int g = lane >> 4, c = lane & 15;
  const int wr = (wid >> 1) * 64, wc = (wid & 1) * 64;

  const int trow = tid >> 3;
  const int tcolb = (tid & 7) << 4;
  const int swr = (c & 7) << 4;
  f32x4 acc[4][4] = {};

#define STAGE_AB(buf, kk0)                                                            \
  _Pragma("unroll") for (int p = 0; p < 4; ++p) {                                     \
    const int row = p * 32 + trow;                                                    \
    const int scol = tcolb ^ ((row & 7) << 4);                                        \
    __builtin_amdgcn_global_load_lds(                                                 \
        (gvoid*)((const char*)A + ((size_t)(m0 + row) * DMODEL + (kk0)) * 2 + scol),  \
        (lvoid*)((char*)&As[buf][0] + row * 128 + tcolb), 16, 0, 0);                  \
    __builtin_amdgcn_global_load_lds(                                                 \
        (gvoid*)((const char*)Bt + ((size_t)(n0 + row) * DMODEL + (kk0)) * 2 + scol), \
        (lvoid*)((char*)&Bs[buf][0] + row * 128 + tcolb), 16, 0, 0);                  \
  }

  STAGE_AB(0, 0);
  STAGE_AB(1, 64);
  __syncthreads();

  for (int t = 0; t < 16; ++t) {
    const int cur = t & 1;
    short8 af[4][2], bfr[4][2];
#pragma unroll
    for (int kk = 0; kk < 2; ++kk) {
#pragma unroll
      for (int mi = 0; mi < 4; ++mi)
        af[mi][kk] = *(const short8*)((const char*)&As[cur][0] + (wr + mi * 16 + c) * 128 + ((kk * 64 + g * 16) ^ swr));
#pragma unroll
      for (int ni = 0; ni < 4; ++ni)
        bfr[ni][kk] = *(const short8*)((const char*)&Bs[cur][0] + (wc + ni * 16 + c) * 128 + ((kk * 64 + g * 16) ^ swr));
    }
    __builtin_amdgcn_s_setprio(1);
#pragma unroll
    for (int kk = 0; kk < 2; ++kk)
#pragma unroll
      for (int mi = 0; mi < 4; ++mi)
#pragma unroll
        for (int ni = 0; ni < 4; ++ni)
          acc[mi][ni] = mfma16(af[mi][kk], bfr[ni][kk], acc[mi][ni]);
    __builtin_amdgcn_s_setprio(0);
    __syncthreads();
    if (t < 14) STAGE_AB(cur, (t + 2) * 64);
  }
#undef STAGE_AB

  for (int ni = 0; ni < 4; ++ni) {
    const int colg = n0 + wc + ni * 16 + c;
    const float bv = bias[colg];
    for (int mi = 0; mi < 4; ++mi) {
      const int rowb = m0 + wr + mi * 16 + g * 4;
      for (int j = 0; j < 4; ++j)
        C[(size_t)(rowb + j) * DMODEL + colg] = acc[mi][ni][j] + bv;
    }
  }
}

// ---------------- flash attention v10: R8 structure + counted-vmcnt barriers ----------------
// Exactly R8's softmax/fragment discipline (loads just-before-use; VALU row-sum)
// with v8's K 3-buffer / V 2-buffer counted-vmcnt pipeline (the isolated +2us).
__global__ __launch_bounds__(256, 4) void attn_kernel(const u16* __restrict__ Q,
                                                      const u16* __restrict__ K,
                                                      const u16* __restrict__ Vt,
                                                      u16* __restrict__ X) {
  __shared__ char Kls[3][8192];
  __shared__ char Vls[2][8192];
  const int tid = threadIdx.x;
  const int lane = tid & 63, wid = tid >> 6;
  const int c5 = lane & 31, hi = lane >> 5;

  const int blk = blockIdx.x;
  const int work = (blk & 7) * 128 + (blk >> 3);
  const int qt = work & 15, bh = work >> 4;

  const int q0 = qt * 128 + wid * 32;
  const u16* qb = Q + (size_t)bh * SEQ * DKH;
  const char* kbB = (const char*)(K + (size_t)bh * SEQ * DKH);
  const char* vbB = (const char*)(Vt + (size_t)bh * DKH * SEQ);

  short8 qf[4];
#pragma unroll
  for (int ks = 0; ks < 4; ++ks)
    qf[ks] = *(const short8*)(qb + (size_t)(q0 + c5) * DKH + ks * 16 + hi * 8);

  const int srow = tid >> 3;
  const int scolb = (tid & 7) << 4;
  const int scol = scolb ^ ((srow & 7) << 4);

  const int fswz = (c5 & 7) << 4;
  int cofs[4];
#pragma unroll
  for (int ks = 0; ks < 4; ++ks) cofs[ks] = ((ks * 32 + hi * 16) ^ fswz);

  f32x16 oacc[2] = {};
  float lrun = 0.f;

#define STAGE_K(t, dst)                                                         \
  _Pragma("unroll") for (int r32 = 0; r32 < 64; r32 += 32)                      \
      __builtin_amdgcn_global_load_lds(                                         \
          (gvoid*)(kbB + ((size_t)(t) * 64 + r32 + srow) * 128 + scol),         \
          (lvoid*)((dst) + (r32 + srow) * 128 + scolb), 16, 0, 0);
#define STAGE_V(t, dst)                                                         \
  _Pragma("unroll") for (int r32 = 0; r32 < 64; r32 += 32)                      \
      __builtin_amdgcn_global_load_lds(                                         \
          (gvoid*)(vbB + (size_t)(r32 + srow) * (SEQ * 2) + (size_t)(t) * 128 + scol), \
          (lvoid*)((dst) + (r32 + srow) * 128 + scolb), 16, 0, 0);

  // prologue: V(0), K(0), K(1); counted wait leaves K(1) in flight
  STAGE_V(0, Vls[0]);
  STAGE_K(0, Kls[0]);
  STAGE_K(1, Kls[1]);
  asm volatile("s_waitcnt vmcnt(2)" ::: "memory");
  __builtin_amdgcn_s_barrier();
  __builtin_amdgcn_sched_barrier(0);

  char* pk0 = Kls[0];
  char* pk1 = Kls[1];
  char* pk2 = Kls[2];

  for (int t = 0; t < 32; ++t) {
    // issue next-tile loads: V first, K second (FIFO order for counted vmcnt)
    if (t < 31) STAGE_V(t + 1, Vls[(t + 1) & 1]);
    if (t < 30) STAGE_K(t + 2, pk2);

    // S^T = K * Q^T (K fragments read just-before-use)
    f32x16 sacc[2];
    __builtin_amdgcn_s_setprio(1);
#pragma unroll
    for (int kt = 0; kt < 2; ++kt) {
      short8 kf[4];
#pragma unroll
      for (int ks = 0; ks < 4; ++ks)
        kf[ks] = *(const short8*)(pk0 + (kt * 32 + c5) * 128 + cofs[ks]);
      sacc[kt] = (f32x16){};
#pragma unroll
      for (int ks = 0; ks < 4; ++ks)
        sacc[kt] = mfma32(kf[ks], qf[ks], sacc[kt]);
    }
    __builtin_amdgcn_s_setprio(0);

    // softmax (no max): p = exp2(s); row-sum on VALU; pack to bf16
    float rs = 0.f;
    u32 W[2][8];
#pragma unroll
    for (int kt = 0; kt < 2; ++kt)
#pragma unroll
      for (int j = 0; j < 8; ++j) {
        float p0 = fexp2(sacc[kt][2 * j]);
        float p1 = fexp2(sacc[kt][2 * j + 1]);
        rs += p0 + p1;
        W[kt][j] = cvtpk(p0, p1);
      }
    rs += __shfl_xor(rs, 32, 64);
    lrun += rs;

    short8 pa[4];
#pragma unroll
    for (int ks = 0; ks < 4; ++ks) {
      const int kt = ks >> 1, l4 = (ks & 1) * 4;
      u32 a0 = W[kt][l4 + 0], b0 = W[kt][l4 + 2];
      u32 a1 = W[kt][l4 + 1], b1 = W[kt][l4 + 3];
      pswap(a0, b0);
      pswap(a1, b1);
      u32 tmp[4] = {a0, a1, b0, b1};
      pa[ks] = *(const short8*)tmp;
    }

    // PV (V fragments read just-before-use)
    const char* bV = Vls[t & 1];
    __builtin_amdgcn_s_setprio(1);
#pragma unroll
    for (int ks = 0; ks < 4; ++ks)
#pragma unroll
      for (int dkt = 0; dkt < 2; ++dkt) {
        short8 vf = *(const short8*)(bV + (dkt * 32 + c5) * 128 + cofs[ks]);
        oacc[dkt] = mfma32(pa[ks], vf, oacc[dkt]);
      }
    __builtin_amdgcn_s_setprio(0);

    // counted wait: V(t+1)/K(t+1) landed; K(t+2) stays in flight
    if (t < 30) {
      asm volatile("s_waitcnt vmcnt(2)" ::: "memory");
    } else {
      asm volatile("s_waitcnt vmcnt(0)" ::: "memory");
    }
    __builtin_amdgcn_s_barrier();
    __builtin_amdgcn_sched_barrier(0);

    char* tmpk = pk0;
    pk0 = pk1;
    pk1 = pk2;
    pk2 = tmpk;
  }

#undef STAGE_K
#undef STAGE_V

  // epilogue
  const int b = bh >> 4, h = bh & 15;
  const float inv = 1.0f / lrun;
#pragma unroll
  for (int r = 0; r < 16; ++r) {
    const int qrow = (r & 3) + 8 * (r >> 2) + 4 * hi;
    const float linv = __shfl(inv, qrow, 64);
    const size_t rowbase = ((size_t)(b * SEQ) + q0 + qrow) * DMODEL + h * DKH;
#pragma unroll
    for (int dkt = 0; dkt < 2; ++dkt)
      X[rowbase + dkt * 32 + c5] = f2bf(oacc[dkt][r] * linv);
  }
}

extern "C" void kernel_launch(void* const* d_in, const int* in_sizes, int n_in,
                              void* d_out, int out_size, void* d_ws, size_t ws_size,
                              hipStream_t stream) {
  (void)in_sizes; (void)n_in; (void)out_size; (void)ws_size;
  const float* query = (const float*)d_in[0];
  const float* key   = (const float*)d_in[1];
  const float* value = (const float*)d_in[2];
  const float* Wq = (const float*)d_in[3];
  const float* bq = (const float*)d_in[4];
  const float* Wk = (const float*)d_in[5];
  const float* bk = (const float*)d_in[6];
  const float* Wv = (const float*)d_in[7];
  const float* bv = (const float*)d_in[8];
  const float* Wo = (const float*)d_in[9];
  const float* bo = (const float*)d_in[10];
  float* out = (float*)d_out;

  char* ws = (char*)d_ws;
  const size_t MB = 1024 * 1024;
  u16* WT  = (u16*)ws;                  // 0-8 MB: WqT, WkT, WvT, WoT
  u16* Qf  = (u16*)(ws + 8 * MB);       // 8-24  bf16 query
  u16* Kf  = (u16*)(ws + 24 * MB);      // 24-40 bf16 key
  u16* Vf  = (u16*)(ws + 40 * MB);      // 40-56 bf16 value
  u16* Qb  = (u16*)(ws + 56 * MB);      // 56-72
  u16* Kb  = (u16*)(ws + 72 * MB);      // 72-88
  u16* Vtb = (u16*)(ws + 88 * MB);      // 88-104
  u16* Xb  = (u16*)(ws + 8 * MB);       // aliases Qf (dead after gemm_qkv)

  prep_kernel<<<dim3(1024, 1, 4), 256, 0, stream>>>(query, key, value, Wq, Wk, Wv, Wo,
                                                    Qf, Kf, Vf, WT);
  gemm_qkv<<<dim3(1536), 256, 0, stream>>>(Qf, Kf, Vf, WT, bq, bk, bv, Qb, Kb, Vtb);
  attn_kernel<<<dim3(1024), 256, 0, stream>>>(Qb, Kb, Vtb, Xb);
  gemm_out<<<dim3(512), 256, 0, stream>>>(Xb, WT + 3 * 1048576, bo, out);
}